// Round 10
// baseline (1079.406 us; speedup 1.0000x reference)
//
#include <hip/hip_runtime.h>
#include <hip/hip_bf16.h>
#include <cstdint>
#include <cstddef>

// Problem constants (fixed by the reference).
constexpr int kN  = 25000;
constexpr int kE  = 400000;
constexpr int kEN = kE + kN;
constexpr int kD  = 64;
constexpr int kH  = 4;
constexpr int kHD = 256;       // H * DH

typedef __attribute__((ext_vector_type(8))) short short8;
typedef __attribute__((ext_vector_type(4))) float f32x4;

__device__ __forceinline__ float lrelu02(float x){ return x > 0.f ? x : 0.2f*x; }
__device__ __forceinline__ unsigned short f2bf(float f){
  __hip_bfloat16 h = __float2bfloat16(f);
  return *reinterpret_cast<unsigned short*>(&h);
}
__device__ __forceinline__ float bf2f(unsigned short u){
  return __uint_as_float(((unsigned)u) << 16);
}
__device__ __forceinline__ float bf_lo(unsigned u){ return __uint_as_float(u << 16); }
__device__ __forceinline__ float bf_hi(unsigned u){ return __uint_as_float(u & 0xffff0000u); }
__device__ __forceinline__ unsigned pack_bf2(float a, float b){
  return ((unsigned)f2bf(a)) | (((unsigned)f2bf(b)) << 16);
}

// ---------------- CSR build ----------------
__global__ void k_deg(const int* __restrict__ col, int* __restrict__ deg){
  int i = blockIdx.x*256 + threadIdx.x;
  if (i < kE) atomicAdd(&deg[col[i]], 1);
}

__global__ void k_scan(const int* __restrict__ deg, int* __restrict__ col_start){
  __shared__ int lds[1024];
  __shared__ int carry_s;
  int t = threadIdx.x;
  if (t == 0) carry_s = 0;
  __syncthreads();
  for (int base = 0; base < kN; base += 1024){
    int v = (base + t < kN) ? deg[base + t] : 0;
    lds[t] = v; __syncthreads();
    for (int off = 1; off < 1024; off <<= 1){
      int add = (t >= off) ? lds[t - off] : 0;
      __syncthreads();
      lds[t] += add;
      __syncthreads();
    }
    int incl = lds[t];
    int carry = carry_s;
    if (base + t < kN) col_start[base + t] = carry + incl - v;
    __syncthreads();
    if (t == 0) carry_s = carry + lds[1023];
    __syncthreads();
  }
  if (t == 0) col_start[kN] = carry_s;
}

__global__ void k_fill(const int* __restrict__ col, const int* __restrict__ col_start,
                       int* __restrict__ fill, int* __restrict__ edge_ids){
  int i = blockIdx.x*256 + threadIdx.x;
  if (i < kE){
    int c = col[i];
    int p = atomicAdd(&fill[c], 1);
    edge_ids[col_start[c] + p] = i;
  }
}

// rowp / rc2: row (and packed row,col) in permuted (CSR) edge order
__global__ void k_permrc(const int* __restrict__ edge_ids, const int* __restrict__ row,
                         const int* __restrict__ col, int* __restrict__ rowp,
                         int2* __restrict__ rc2){
  int p = blockIdx.x*256 + threadIdx.x;
  if (p < kE){
    int eid = edge_ids[p];
    int r = row[eid], c = col[eid];
    rowp[p] = r;
    rc2[p] = make_int2(r, c);
  }
}

// ---------------- weight prepack ----------------
// WeT[l][j][k] = bf16(We[l][k][j])   (j in [0,256), k in [0,64))
__global__ void k_prep(const float* __restrict__ We, unsigned short* __restrict__ WeT){
  int idx = blockIdx.x*256 + threadIdx.x;
  if (idx >= 3*256*64) return;
  int l = idx >> 14, j = (idx >> 6) & 255, k = idx & 63;
  WeT[idx] = f2bf(We[(size_t)l*16384 + k*256 + j]);
}

// W1cT[l][d][k] = bf16(euW1[l][128+k][d]);  W2T[l][d][k] = bf16(euW2[l][k][d])
__global__ void k_prep2(const float* __restrict__ euW1, const float* __restrict__ euW2,
                        unsigned short* __restrict__ W1cT, unsigned short* __restrict__ W2T){
  int idx = blockIdx.x*256 + threadIdx.x;
  if (idx >= 3*64*64) return;
  int l = idx >> 12, rem = idx & 4095, d = rem >> 6, k = rem & 63;
  W1cT[idx] = f2bf(euW1[(size_t)l*192*64 + (size_t)(128+k)*64 + d]);
  W2T[idx]  = f2bf(euW2[(size_t)l*64*64  + (size_t)k*64 + d]);
}

// ---------------- initial embeddings ----------------
__global__ void k_x0(const float* __restrict__ nf, const float* __restrict__ W,
                     const float* __restrict__ b, float* __restrict__ x){
  int i = blockIdx.x*256 + threadIdx.x;
  if (i >= kN*kD) return;
  int n = i >> 6, d = i & 63;
  float acc = b[d];
#pragma unroll
  for (int k = 0; k < 16; k++) acc += nf[n*16 + k] * W[k*64 + d];
  x[i] = fmaxf(acc, 0.f);
}

// e0 in PERMUTED order, bf16 only
__global__ void k_e0p(const int* __restrict__ edge_ids,
                      const float* __restrict__ ea, const float* __restrict__ W,
                      const float* __restrict__ b,
                      unsigned short* __restrict__ ebf_perm){
  long long i = (long long)blockIdx.x*256 + threadIdx.x;
  if (i >= (long long)kE*kD) return;
  int p = (int)(i >> 6), d = (int)(i & 63);
  int eid = edge_ids[p];
  float acc = b[d];
#pragma unroll
  for (int k = 0; k < 4; k++) acc += ea[eid*4 + k] * W[k*64 + d];
  ebf_perm[i] = f2bf(fmaxf(acc, 0.f));
}

// ---------------- prologue: xl_bf/xr_bf for layer 0 ----------------
#define XLR_NPB 8
__global__ __launch_bounds__(256) void k_xlr(const float* __restrict__ x,
    const float* __restrict__ Wl, const float* __restrict__ bl,
    const float* __restrict__ Wr, const float* __restrict__ br,
    unsigned short* __restrict__ xl_bf, unsigned short* __restrict__ xr_bf){
  __shared__ float xs[XLR_NPB*64];
  int j = threadIdx.x;
  int n0 = blockIdx.x * XLR_NPB;
  for (int i = j; i < XLR_NPB*64; i += 256){
    int n = n0 + (i >> 6);
    xs[i] = (n < kN) ? x[(size_t)n*64 + (i & 63)] : 0.f;
  }
  __syncthreads();
  float accl[XLR_NPB], accr[XLR_NPB];
  float blv = bl[j], brv = br[j];
#pragma unroll
  for (int t = 0; t < XLR_NPB; t++){ accl[t] = blv; accr[t] = brv; }
  for (int k = 0; k < 64; k++){
    float wl = Wl[k*kHD + j], wr = Wr[k*kHD + j];
#pragma unroll
    for (int t = 0; t < XLR_NPB; t++){
      float xv = xs[t*64 + k];
      accl[t] += xv * wl; accr[t] += xv * wr;
    }
  }
#pragma unroll
  for (int t = 0; t < XLR_NPB; t++){
    int n = n0 + t;
    if (n < kN){
      xl_bf[(size_t)n*kHD + j] = f2bf(accl[t]);
      xr_bf[(size_t)n*kHD + j] = f2bf(accr[t]);
    }
  }
}

// ---------------- in-loop: P,Q (layer i) + xl,xr (layer i+1) from one x stage ----------
// P/Q split over thread groups: s=0: P nodes 0-3, s=1: P nodes 4-7, s=2: Q 0-3, s=3: Q 4-7.
__global__ __launch_bounds__(256) void k_xlrpq(const float* __restrict__ x,
    const float* __restrict__ Wl, const float* __restrict__ bl,
    const float* __restrict__ Wr, const float* __restrict__ br,
    const float* __restrict__ W1, const float* __restrict__ b1,
    int do_xlr,
    unsigned short* __restrict__ xl_bf, unsigned short* __restrict__ xr_bf,
    unsigned short* __restrict__ P_bf, unsigned short* __restrict__ Q_bf){
  __shared__ float xs[XLR_NPB*64];
  int j = threadIdx.x;
  int n0 = blockIdx.x * XLR_NPB;
  for (int i = j; i < XLR_NPB*64; i += 256){
    int n = n0 + (i >> 6);
    xs[i] = (n < kN) ? x[(size_t)n*64 + (i & 63)] : 0.f;
  }
  __syncthreads();

  // ---- P/Q (layer i) ----
  int jc = j & 63, s = j >> 6;
  int tb = (s & 1)*4;
  bool isQ = (s >= 2);
  float accpq[4];
  float b1v = isQ ? 0.f : b1[jc];
#pragma unroll
  for (int t = 0; t < 4; t++) accpq[t] = b1v;
  const float* Wpq = W1 + (isQ ? 64*64 : 0);
  for (int k = 0; k < 64; k++){
    float w = Wpq[k*64 + jc];
#pragma unroll
    for (int t = 0; t < 4; t++) accpq[t] += xs[(tb + t)*64 + k] * w;
  }
#pragma unroll
  for (int t = 0; t < 4; t++){
    int n = n0 + tb + t;
    if (n < kN){
      if (isQ) Q_bf[(size_t)n*64 + jc] = f2bf(accpq[t]);
      else     P_bf[(size_t)n*64 + jc] = f2bf(accpq[t]);
    }
  }

  // ---- xl/xr (layer i+1) ----
  if (do_xlr){
    float accl[XLR_NPB], accr[XLR_NPB];
    float blv = bl[j], brv = br[j];
#pragma unroll
    for (int t = 0; t < XLR_NPB; t++){ accl[t] = blv; accr[t] = brv; }
    for (int k = 0; k < 64; k++){
      float wl = Wl[k*kHD + j], wr = Wr[k*kHD + j];
#pragma unroll
      for (int t = 0; t < XLR_NPB; t++){
        float xv = xs[t*64 + k];
        accl[t] += xv * wl; accr[t] += xv * wr;
      }
    }
#pragma unroll
    for (int t = 0; t < XLR_NPB; t++){
      int n = n0 + t;
      if (n < kN){
        xl_bf[(size_t)n*kHD + j] = f2bf(accl[t]);
        xr_bf[(size_t)n*kHD + j] = f2bf(accr[t]);
      }
    }
  }
}

// ---------------- per-layer: e_loop (bf16) = mean of incoming e rows (contiguous) ------
__global__ __launch_bounds__(256) void k_eloop(const unsigned short* __restrict__ ebf_perm,
    const int* __restrict__ col_start, unsigned short* __restrict__ eloop_bf){
  int wave = threadIdx.x >> 6, lane = threadIdx.x & 63;
  int n = blockIdx.x*4 + wave;
  if (n >= kN) return;
  int s0 = col_start[n], s1 = col_start[n+1];
  float acc = 0.f;
  for (int p = s0; p < s1; p++)
    acc += bf2f(ebf_perm[(size_t)p*64 + lane]);
  int dg = s1 - s0;
  eloop_bf[(size_t)n*64 + lane] = f2bf(acc / (float)(dg > 0 ? dg : 1));
}

// ---------------- per-layer: MFMA score kernel, HEAD-PARTITIONED by XCD ----------
// blockIdx&7 = XCD (round-robin dispatch); head = xcd>>1 (2 XCDs per head).
// Each XCD touches only its head's 64-dim slice of xl/xr (3.2MB hot set < 4MB L2).
struct STile {
  short8 b0, b1;
  uint2 xlu[4], xru[4];
};

__device__ __forceinline__ void s_load(int tile, STile& f, int e16, int kb, int h,
    const unsigned short* __restrict__ ebf_perm,
    const unsigned short* __restrict__ eloop_bf,
    const unsigned short* __restrict__ xl_bf,
    const unsigned short* __restrict__ xr_bf,
    const int2* __restrict__ rc2)
{
  int p = tile*16 + e16;
  int pc = (p < kEN) ? p : 0;
  bool isE = pc < kE;
  int2 rc;
  if (isE) rc = rc2[pc];
  else { rc.x = pc - kE; rc.y = pc - kE; }
  const unsigned short* erow = isE ? (ebf_perm + (size_t)pc*64)
                                   : (eloop_bf + (size_t)(pc - kE)*64);
  f.b0 = *(const short8*)(erow + kb*8);
  f.b1 = *(const short8*)(erow + 32 + kb*8);
  const unsigned short* xl_ = xl_bf + (size_t)rc.x*kHD + h*64;
  const unsigned short* xr_ = xr_bf + (size_t)rc.y*kHD + h*64;
#pragma unroll
  for (int mt = 0; mt < 4; mt++){
    f.xlu[mt] = *(const uint2*)(xl_ + mt*16 + kb*4);
    f.xru[mt] = *(const uint2*)(xr_ + mt*16 + kb*4);
  }
}

__device__ __forceinline__ void s_comp(int tile, const STile& f,
    const short8 A[4][2], const uint2 attp[4], int lane, int h,
    float* __restrict__ score)
{
  float sc = 0.f;
#pragma unroll
  for (int mt = 0; mt < 4; mt++){
    f32x4 acc = {0.f,0.f,0.f,0.f};
    acc = __builtin_amdgcn_mfma_f32_16x16x32_bf16(A[mt][0], f.b0, acc, 0, 0, 0);
    acc = __builtin_amdgcn_mfma_f32_16x16x32_bf16(A[mt][1], f.b1, acc, 0, 0, 0);
    sc += lrelu02(acc[0] + bf_lo(f.xlu[mt].x) + bf_lo(f.xru[mt].x)) * bf_lo(attp[mt].x);
    sc += lrelu02(acc[1] + bf_hi(f.xlu[mt].x) + bf_hi(f.xru[mt].x)) * bf_hi(attp[mt].x);
    sc += lrelu02(acc[2] + bf_lo(f.xlu[mt].y) + bf_lo(f.xru[mt].y)) * bf_lo(attp[mt].y);
    sc += lrelu02(acc[3] + bf_hi(f.xlu[mt].y) + bf_hi(f.xru[mt].y)) * bf_hi(attp[mt].y);
  }
  sc += __shfl_xor(sc, 16);
  sc += __shfl_xor(sc, 32);
  int wp = tile*16 + lane;
  if (lane < 16 && wp < kEN) score[(size_t)wp*kH + h] = sc;
}

__global__ __launch_bounds__(256) void k_score_mfma(
    const unsigned short* __restrict__ ebf_perm, // [E][64] permuted
    const unsigned short* __restrict__ eloop_bf, // [N][64]
    const unsigned short* __restrict__ xl_bf,    // [N][256]
    const unsigned short* __restrict__ xr_bf,    // [N][256]
    const int2* __restrict__ rc2,
    const unsigned short* __restrict__ WeT,      // [256][64] bf16
    const float* __restrict__ att,               // [4][64]
    float* __restrict__ score)                   // [EN][4] permuted
{
  int lane = threadIdx.x & 63;
  int wv   = threadIdx.x >> 6;
  int e16  = lane & 15;
  int kb   = lane >> 4;

  int b = blockIdx.x;                 // grid = 2048
  int xcd = b & 7;
  int h = xcd >> 1;                   // head for this XCD
  int sub = ((b >> 3) << 1) | (xcd & 1);   // 0..511 within head
  int wid = sub*4 + wv;               // 0..2047 within head

  short8 A[4][2];
  uint2 attp[4];
#pragma unroll
  for (int mt = 0; mt < 4; mt++){
    const unsigned short* arow = WeT + (size_t)(h*64 + mt*16 + e16)*64 + kb*8;
    A[mt][0] = *(const short8*)(arow);
    A[mt][1] = *(const short8*)(arow + 32);
    f32x4 av = *(const f32x4*)(att + h*64 + mt*16 + kb*4);
    attp[mt].x = pack_bf2(av[0], av[1]);
    attp[mt].y = pack_bf2(av[2], av[3]);
  }

  constexpr int NT = (kEN + 15)/16;
  for (int tile = wid; tile < NT; tile += 2048){
    STile f;
    s_load(tile, f, e16, kb, h, ebf_perm, eloop_bf, xl_bf, xr_bf, rc2);
    s_comp(tile, f, A, attp, lane, h, score);
  }
}

// ---------------- per-layer: FUSED segment softmax + aggregate + LN (wave-per-node) ----
__global__ __launch_bounds__(256) void k_agg_ln(
    const unsigned short* __restrict__ xl_bf, const float* __restrict__ score,
    const int* __restrict__ rowp, const int* __restrict__ col_start,
    const float* __restrict__ conv_b, const float* __restrict__ ln_g,
    const float* __restrict__ ln_b, float* __restrict__ x){
  int wv = threadIdx.x >> 6, l = threadIdx.x & 63;
  int n = blockIdx.x*4 + wv;
  if (n >= kN) return;
  int h = l >> 4;
  int s0 = col_start[n], s1 = col_start[n+1];

  float sc_self = score[(size_t)(kE + n)*kH + h];
  float m = sc_self;
  for (int p = s0; p < s1; p++)
    m = fmaxf(m, score[(size_t)p*kH + h]);

  float w0 = __expf(sc_self - m);
  float s = w0;
  float a0, a1, a2, a3;
  {
    uint2 u = *(const uint2*)(xl_bf + (size_t)n*kHD + l*4);
    a0 = w0*bf_lo(u.x); a1 = w0*bf_hi(u.x);
    a2 = w0*bf_lo(u.y); a3 = w0*bf_hi(u.y);
  }
  int p = s0;
  for (; p + 4 <= s1; p += 4){
    float e0 = __expf(score[(size_t)(p+0)*kH + h] - m);
    float e1 = __expf(score[(size_t)(p+1)*kH + h] - m);
    float e2 = __expf(score[(size_t)(p+2)*kH + h] - m);
    float e3 = __expf(score[(size_t)(p+3)*kH + h] - m);
    int r0 = rowp[p], r1 = rowp[p+1], r2 = rowp[p+2], r3 = rowp[p+3];
    uint2 u0 = *(const uint2*)(xl_bf + (size_t)r0*kHD + l*4);
    uint2 u1 = *(const uint2*)(xl_bf + (size_t)r1*kHD + l*4);
    uint2 u2 = *(const uint2*)(xl_bf + (size_t)r2*kHD + l*4);
    uint2 u3 = *(const uint2*)(xl_bf + (size_t)r3*kHD + l*4);
    s += e0 + e1 + e2 + e3;
    a0 += e0*bf_lo(u0.x) + e1*bf_lo(u1.x) + e2*bf_lo(u2.x) + e3*bf_lo(u3.x);
    a1 += e0*bf_hi(u0.x) + e1*bf_hi(u1.x) + e2*bf_hi(u2.x) + e3*bf_hi(u3.x);
    a2 += e0*bf_lo(u0.y) + e1*bf_lo(u1.y) + e2*bf_lo(u2.y) + e3*bf_lo(u3.y);
    a3 += e0*bf_hi(u0.y) + e1*bf_hi(u1.y) + e2*bf_hi(u2.y) + e3*bf_hi(u3.y);
  }
  for (; p < s1; p++){
    float ew = __expf(score[(size_t)p*kH + h] - m);
    int r = rowp[p];
    uint2 u = *(const uint2*)(xl_bf + (size_t)r*kHD + l*4);
    s += ew;
    a0 += ew*bf_lo(u.x); a1 += ew*bf_hi(u.x);
    a2 += ew*bf_lo(u.y); a3 += ew*bf_hi(u.y);
  }
  float inv = 1.f / s;
  a0 *= inv; a1 *= inv; a2 *= inv; a3 *= inv;
  a0 += __shfl_xor(a0, 16); a0 += __shfl_xor(a0, 32);
  a1 += __shfl_xor(a1, 16); a1 += __shfl_xor(a1, 32);
  a2 += __shfl_xor(a2, 16); a2 += __shfl_xor(a2, 32);
  a3 += __shfl_xor(a3, 16); a3 += __shfl_xor(a3, 32);
  int d0 = (l & 15)*4;
  f32x4 cb = *(const f32x4*)(conv_b + d0);
  f32x4 xv = *(const f32x4*)(x + (size_t)n*64 + d0);
  float y0 = xv[0] + a0*0.25f + cb[0];
  float y1 = xv[1] + a1*0.25f + cb[1];
  float y2 = xv[2] + a2*0.25f + cb[2];
  float y3 = xv[3] + a3*0.25f + cb[3];
  float part = y0 + y1 + y2 + y3;
  part += __shfl_xor(part, 1); part += __shfl_xor(part, 2);
  part += __shfl_xor(part, 4); part += __shfl_xor(part, 8);
  float mu = part * (1.f/64.f);
  float f0 = y0 - mu, f1 = y1 - mu, f2 = y2 - mu, f3 = y3 - mu;
  float vp = f0*f0 + f1*f1 + f2*f2 + f3*f3;
  vp += __shfl_xor(vp, 1); vp += __shfl_xor(vp, 2);
  vp += __shfl_xor(vp, 4); vp += __shfl_xor(vp, 8);
  float rstd = rsqrtf(vp * (1.f/64.f) + 1e-5f);
  f32x4 gv = *(const f32x4*)(ln_g + d0);
  f32x4 bv = *(const f32x4*)(ln_b + d0);
  if (l < 16){
    f32x4 o;
    o[0] = fmaxf(f0*rstd*gv[0] + bv[0], 0.f);
    o[1] = fmaxf(f1*rstd*gv[1] + bv[1], 0.f);
    o[2] = fmaxf(f2*rstd*gv[2] + bv[2], 0.f);
    o[3] = fmaxf(f3*rstd*gv[3] + bv[3], 0.f);
    *(f32x4*)(x + (size_t)n*64 + d0) = o;
  }
}

// ---------------- per-layer: edge MLP via MFMA (bf16 residual, bf16 P/Q) ----------------
__global__ __launch_bounds__(256) void k_mlp_mfma(
    unsigned short* __restrict__ ebf_perm,
    float* __restrict__ eout_scatter,
    const int* __restrict__ edge_ids,
    const unsigned short* __restrict__ P_bf, const unsigned short* __restrict__ Q_bf,
    const unsigned short* __restrict__ W1cT,  // [64 d][64 k] bf16
    const unsigned short* __restrict__ W2T,   // [64 d][64 k] bf16
    const float* __restrict__ b2,
    const int2* __restrict__ rc2)
{
  __shared__ unsigned short Hl[4][1024];      // 2KB per wave
  int lane = threadIdx.x & 63, wv = threadIdx.x >> 6;
  int e16 = lane & 15, g = lane >> 4;
  int swz = (e16 & 7) << 4;
  char* Hw = (char*)Hl[wv];
  bool last = (eout_scatter != nullptr);

  short8 a1[4][2], a2[4][2];
#pragma unroll
  for (int mt = 0; mt < 4; mt++){
#pragma unroll
    for (int c = 0; c < 2; c++){
      a1[mt][c] = *(const short8*)(W1cT + (size_t)(mt*16 + e16)*64 + c*32 + g*8);
      a2[mt][c] = *(const short8*)(W2T  + (size_t)(mt*16 + e16)*64 + c*32 + g*8);
    }
  }
  f32x4 b2v[4];
#pragma unroll
  for (int mt = 0; mt < 4; mt++) b2v[mt] = *(const f32x4*)(b2 + mt*16 + g*4);

  int wid = (blockIdx.x*256 + threadIdx.x) >> 6;
  int nw  = (gridDim.x*256) >> 6;
  for (int tile = wid; tile < kE/16; tile += nw){
    int p = tile*16 + e16;
    int2 rc = rc2[p];
    const unsigned short* erow = ebf_perm + (size_t)p*64;
    short8 eb0 = *(const short8*)(erow + g*8);
    short8 eb1 = *(const short8*)(erow + 32 + g*8);
    const unsigned short* Pr = P_bf + (size_t)rc.x*64;
    const unsigned short* Qc = Q_bf + (size_t)rc.y*64;

#pragma unroll
    for (int mt = 0; mt < 4; mt++){
      f32x4 acc = {0.f,0.f,0.f,0.f};
      acc = __builtin_amdgcn_mfma_f32_16x16x32_bf16(a1[mt][0], eb0, acc, 0, 0, 0);
      acc = __builtin_amdgcn_mfma_f32_16x16x32_bf16(a1[mt][1], eb1, acc, 0, 0, 0);
      uint2 pu = *(const uint2*)(Pr + mt*16 + g*4);
      uint2 qu = *(const uint2*)(Qc + mt*16 + g*4);
      float h0 = fmaxf(acc[0] + bf_lo(pu.x) + bf_lo(qu.x), 0.f);
      float h1 = fmaxf(acc[1] + bf_hi(pu.x) + bf_hi(qu.x), 0.f);
      float h2 = fmaxf(acc[2] + bf_lo(pu.y) + bf_lo(qu.y), 0.f);
      float h3 = fmaxf(acc[3] + bf_hi(pu.y) + bf_hi(qu.y), 0.f);
      uint2 pk; pk.x = pack_bf2(h0, h1); pk.y = pack_bf2(h2, h3);
      *(uint2*)(Hw + (((e16 << 7) + (mt << 5) + (g << 3)) ^ swz)) = pk;
    }
    short8 hb0 = *(const short8*)(Hw + (((e16 << 7)      + (g << 4)) ^ swz));
    short8 hb1 = *(const short8*)(Hw + (((e16 << 7) + 64 + (g << 4)) ^ swz));

    int oe = last ? edge_ids[p] : 0;
#pragma unroll
    for (int mt = 0; mt < 4; mt++){
      f32x4 o = {0.f,0.f,0.f,0.f};
      o = __builtin_amdgcn_mfma_f32_16x16x32_bf16(a2[mt][0], hb0, o, 0, 0, 0);
      o = __builtin_amdgcn_mfma_f32_16x16x32_bf16(a2[mt][1], hb1, o, 0, 0, 0);
      size_t off = (size_t)p*64 + mt*16 + g*4;
      uint2 u = *(const uint2*)(ebf_perm + off);
      f32x4 eo;
      eo[0] = bf_lo(u.x); eo[1] = bf_hi(u.x); eo[2] = bf_lo(u.y); eo[3] = bf_hi(u.y);
      f32x4 ne;
      ne[0] = fmaxf(eo[0] + o[0] + b2v[mt][0], 0.f);
      ne[1] = fmaxf(eo[1] + o[1] + b2v[mt][1], 0.f);
      ne[2] = fmaxf(eo[2] + o[2] + b2v[mt][2], 0.f);
      ne[3] = fmaxf(eo[3] + o[3] + b2v[mt][3], 0.f);
      if (!last){
        uint2 po; po.x = pack_bf2(ne[0], ne[1]); po.y = pack_bf2(ne[2], ne[3]);
        *(uint2*)(ebf_perm + off) = po;
      } else {
        *(f32x4*)(eout_scatter + (size_t)oe*64 + mt*16 + g*4) = ne;
      }
    }
  }
}

// ---------------- host ----------------
extern "C" void kernel_launch(void* const* d_in, const int* in_sizes, int n_in,
                              void* d_out, int out_size, void* d_ws, size_t ws_size,
                              hipStream_t stream) {
  const float* node_feat = (const float*)d_in[0];
  const int*   edge_idx  = (const int*)d_in[1];
  const float* edge_attr = (const float*)d_in[2];
  const float* W_node = (const float*)d_in[3];
  const float* b_node = (const float*)d_in[4];
  const float* W_edge = (const float*)d_in[5];
  const float* b_edge = (const float*)d_in[6];
  const float* Wl   = (const float*)d_in[7];
  const float* bl   = (const float*)d_in[8];
  const float* Wr   = (const float*)d_in[9];
  const float* br   = (const float*)d_in[10];
  const float* We   = (const float*)d_in[11];
  const float* att  = (const float*)d_in[12];
  const float* cvb  = (const float*)d_in[13];
  const float* lng  = (const float*)d_in[14];
  const float* lnb  = (const float*)d_in[15];
  const float* euW1 = (const float*)d_in[16];
  const float* eub1 = (const float*)d_in[17];
  const float* euW2 = (const float*)d_in[18];
  const float* eub2 = (const float*)d_in[19];

  const int* row = edge_idx;
  const int* col = edge_idx + kE;

  float* x = (float*)d_out;                       // N x 64
  float* e_out = (float*)d_out + (size_t)kN*kD;   // E x 64 (written by final scatter)

  char* p = (char*)d_ws;
  auto carve = [&](size_t bytes)->void*{
    void* r = (void*)p;
    p += (bytes + 255) & ~(size_t)255;
    return r;
  };
  unsigned short* xl_bf    = (unsigned short*)carve((size_t)kN*kHD*2);
  unsigned short* xr_bf    = (unsigned short*)carve((size_t)kN*kHD*2);
  unsigned short* P_bf     = (unsigned short*)carve((size_t)kN*kD*2);
  unsigned short* Q_bf     = (unsigned short*)carve((size_t)kN*kD*2);
  unsigned short* ebf_perm = (unsigned short*)carve((size_t)kE*kD*2);
  unsigned short* eloop_bf = (unsigned short*)carve((size_t)kN*kD*2);
  unsigned short* WeT      = (unsigned short*)carve((size_t)3*kHD*kD*2);
  unsigned short* W1cT     = (unsigned short*)carve((size_t)3*kD*kD*2);
  unsigned short* W2T      = (unsigned short*)carve((size_t)3*kD*kD*2);
  float* score  = (float*)carve((size_t)kEN*kH*4);
  int* deg      = (int*)carve((size_t)kN*4);
  int* col_start= (int*)carve((size_t)(kN+1)*4);
  int* fill     = (int*)carve((size_t)kN*4);
  int* edge_ids = (int*)carve((size_t)kE*4);
  int* rowp     = (int*)carve((size_t)kE*4);
  int2* rc2     = (int2*)carve((size_t)kE*8);

  // CSR build (graph is layer-invariant)
  hipMemsetAsync(deg, 0, (size_t)kN*4, stream);
  hipMemsetAsync(fill, 0, (size_t)kN*4, stream);
  k_deg<<<(kE+255)/256, 256, 0, stream>>>(col, deg);
  k_scan<<<1, 1024, 0, stream>>>(deg, col_start);
  k_fill<<<(kE+255)/256, 256, 0, stream>>>(col, col_start, fill, edge_ids);
  k_permrc<<<(kE+255)/256, 256, 0, stream>>>(edge_ids, row, col, rowp, rc2);

  // weight prepack + initial embeddings
  k_prep<<<192, 256, 0, stream>>>(We, WeT);
  k_prep2<<<48, 256, 0, stream>>>(euW1, euW2, W1cT, W2T);
  k_x0<<<(kN*kD+255)/256, 256, 0, stream>>>(node_feat, W_node, b_node, x);
  k_e0p<<<(int)(((size_t)kE*kD+255)/256), 256, 0, stream>>>(edge_ids, edge_attr, W_edge,
                                                            b_edge, ebf_perm);
  // xl/xr for layer 0
  k_xlr<<<(kN + XLR_NPB - 1)/XLR_NPB, 256, 0, stream>>>(x, Wl, bl, Wr, br, xl_bf, xr_bf);

  for (int i = 0; i < 3; i++){
    const float* att_i = att + (size_t)i*kHD;
    const float* cvb_i = cvb + (size_t)i*kD;
    const float* lng_i = lng + (size_t)i*kD;
    const float* lnb_i = lnb + (size_t)i*kD;
    const float* W1_i  = euW1 + (size_t)i*192*64;
    const float* b1_i  = eub1 + (size_t)i*kD;
    const float* b2_i  = eub2 + (size_t)i*kD;
    const unsigned short* WeT_i  = WeT  + (size_t)i*kHD*kD;
    const unsigned short* W1cT_i = W1cT + (size_t)i*kD*kD;
    const unsigned short* W2T_i  = W2T  + (size_t)i*kD*kD;
    // next layer's node transforms (valid only for i<2)
    int ni = (i < 2) ? (i + 1) : 0;
    const float* Wl_n = Wl + (size_t)ni*kD*kHD;
    const float* bl_n = bl + (size_t)ni*kHD;
    const float* Wr_n = Wr + (size_t)ni*kD*kHD;
    const float* br_n = br + (size_t)ni*kHD;

    k_eloop<<<(kN + 3)/4, 256, 0, stream>>>(ebf_perm, col_start, eloop_bf);
    k_score_mfma<<<2048, 256, 0, stream>>>(ebf_perm, eloop_bf, xl_bf, xr_bf,
                                           rc2, WeT_i, att_i, score);
    k_agg_ln<<<(kN + 3)/4, 256, 0, stream>>>(xl_bf, score, rowp, col_start,
                                             cvb_i, lng_i, lnb_i, x);
    // P/Q for layer i + xl/xr for layer i+1 (one x pass)
    k_xlrpq<<<(kN + XLR_NPB - 1)/XLR_NPB, 256, 0, stream>>>(x, Wl_n, bl_n, Wr_n, br_n,
                                                            W1_i, b1_i, (i < 2) ? 1 : 0,
                                                            xl_bf, xr_bf, P_bf, Q_bf);
    k_mlp_mfma<<<2048, 256, 0, stream>>>(ebf_perm, (i < 2) ? nullptr : e_out,
                                         edge_ids, P_bf, Q_bf, W1cT_i, W2T_i, b2_i,
                                         rc2);
  }
}

// Round 11
// 980.781 us; speedup vs baseline: 1.1006x; 1.1006x over previous
//
#include <hip/hip_runtime.h>
#include <hip/hip_bf16.h>
#include <cstdint>
#include <cstddef>

// Problem constants (fixed by the reference).
constexpr int kN  = 25000;
constexpr int kE  = 400000;
constexpr int kEN = kE + kN;
constexpr int kD  = 64;
constexpr int kH  = 4;
constexpr int kHD = 256;       // H * DH

typedef __attribute__((ext_vector_type(8))) short short8;
typedef __attribute__((ext_vector_type(4))) float f32x4;

__device__ __forceinline__ float lrelu02(float x){ return x > 0.f ? x : 0.2f*x; }
__device__ __forceinline__ unsigned short f2bf(float f){
  __hip_bfloat16 h = __float2bfloat16(f);
  return *reinterpret_cast<unsigned short*>(&h);
}
__device__ __forceinline__ float bf2f(unsigned short u){
  return __uint_as_float(((unsigned)u) << 16);
}
__device__ __forceinline__ float bf_lo(unsigned u){ return __uint_as_float(u << 16); }
__device__ __forceinline__ float bf_hi(unsigned u){ return __uint_as_float(u & 0xffff0000u); }
__device__ __forceinline__ unsigned pack_bf2(float a, float b){
  return ((unsigned)f2bf(a)) | (((unsigned)f2bf(b)) << 16);
}

// ---------------- CSR build ----------------
__global__ void k_deg(const int* __restrict__ col, int* __restrict__ deg){
  int i = blockIdx.x*256 + threadIdx.x;
  if (i < kE) atomicAdd(&deg[col[i]], 1);
}

__global__ void k_scan(const int* __restrict__ deg, int* __restrict__ col_start){
  __shared__ int lds[1024];
  __shared__ int carry_s;
  int t = threadIdx.x;
  if (t == 0) carry_s = 0;
  __syncthreads();
  for (int base = 0; base < kN; base += 1024){
    int v = (base + t < kN) ? deg[base + t] : 0;
    lds[t] = v; __syncthreads();
    for (int off = 1; off < 1024; off <<= 1){
      int add = (t >= off) ? lds[t - off] : 0;
      __syncthreads();
      lds[t] += add;
      __syncthreads();
    }
    int incl = lds[t];
    int carry = carry_s;
    if (base + t < kN) col_start[base + t] = carry + incl - v;
    __syncthreads();
    if (t == 0) carry_s = carry + lds[1023];
    __syncthreads();
  }
  if (t == 0) col_start[kN] = carry_s;
}

__global__ void k_fill(const int* __restrict__ col, const int* __restrict__ col_start,
                       int* __restrict__ fill, int* __restrict__ edge_ids){
  int i = blockIdx.x*256 + threadIdx.x;
  if (i < kE){
    int c = col[i];
    int p = atomicAdd(&fill[c], 1);
    edge_ids[col_start[c] + p] = i;
  }
}

// rowp / rc2: row (and packed row,col) in permuted (CSR) edge order
__global__ void k_permrc(const int* __restrict__ edge_ids, const int* __restrict__ row,
                         const int* __restrict__ col, int* __restrict__ rowp,
                         int2* __restrict__ rc2){
  int p = blockIdx.x*256 + threadIdx.x;
  if (p < kE){
    int eid = edge_ids[p];
    int r = row[eid], c = col[eid];
    rowp[p] = r;
    rc2[p] = make_int2(r, c);
  }
}

// ---------------- weight prepack ----------------
// WeT[l][j][k] = bf16(We[l][k][j])   (j in [0,256), k in [0,64))
__global__ void k_prep(const float* __restrict__ We, unsigned short* __restrict__ WeT){
  int idx = blockIdx.x*256 + threadIdx.x;
  if (idx >= 3*256*64) return;
  int l = idx >> 14, j = (idx >> 6) & 255, k = idx & 63;
  WeT[idx] = f2bf(We[(size_t)l*16384 + k*256 + j]);
}

// W1cT[l][d][k] = bf16(euW1[l][128+k][d]);  W2T[l][d][k] = bf16(euW2[l][k][d])
__global__ void k_prep2(const float* __restrict__ euW1, const float* __restrict__ euW2,
                        unsigned short* __restrict__ W1cT, unsigned short* __restrict__ W2T){
  int idx = blockIdx.x*256 + threadIdx.x;
  if (idx >= 3*64*64) return;
  int l = idx >> 12, rem = idx & 4095, d = rem >> 6, k = rem & 63;
  W1cT[idx] = f2bf(euW1[(size_t)l*192*64 + (size_t)(128+k)*64 + d]);
  W2T[idx]  = f2bf(euW2[(size_t)l*64*64  + (size_t)k*64 + d]);
}

// ---------------- initial embeddings ----------------
__global__ void k_x0(const float* __restrict__ nf, const float* __restrict__ W,
                     const float* __restrict__ b, float* __restrict__ x){
  int i = blockIdx.x*256 + threadIdx.x;
  if (i >= kN*kD) return;
  int n = i >> 6, d = i & 63;
  float acc = b[d];
#pragma unroll
  for (int k = 0; k < 16; k++) acc += nf[n*16 + k] * W[k*64 + d];
  x[i] = fmaxf(acc, 0.f);
}

// e0 in PERMUTED order, bf16 only
__global__ void k_e0p(const int* __restrict__ edge_ids,
                      const float* __restrict__ ea, const float* __restrict__ W,
                      const float* __restrict__ b,
                      unsigned short* __restrict__ ebf_perm){
  long long i = (long long)blockIdx.x*256 + threadIdx.x;
  if (i >= (long long)kE*kD) return;
  int p = (int)(i >> 6), d = (int)(i & 63);
  int eid = edge_ids[p];
  float acc = b[d];
#pragma unroll
  for (int k = 0; k < 4; k++) acc += ea[eid*4 + k] * W[k*64 + d];
  ebf_perm[i] = f2bf(fmaxf(acc, 0.f));
}

// ---------------- per-layer: xl_bf = bf16(x@Wl+bl), xr_bf = bf16(x@Wr+br) ----------------
#define XLR_NPB 8
__global__ __launch_bounds__(256) void k_xlr(const float* __restrict__ x,
    const float* __restrict__ Wl, const float* __restrict__ bl,
    const float* __restrict__ Wr, const float* __restrict__ br,
    unsigned short* __restrict__ xl_bf, unsigned short* __restrict__ xr_bf){
  __shared__ float xs[XLR_NPB*64];
  int j = threadIdx.x;
  int n0 = blockIdx.x * XLR_NPB;
  for (int i = j; i < XLR_NPB*64; i += 256){
    int n = n0 + (i >> 6);
    xs[i] = (n < kN) ? x[(size_t)n*64 + (i & 63)] : 0.f;
  }
  __syncthreads();
  float accl[XLR_NPB], accr[XLR_NPB];
  float blv = bl[j], brv = br[j];
#pragma unroll
  for (int t = 0; t < XLR_NPB; t++){ accl[t] = blv; accr[t] = brv; }
  for (int k = 0; k < 64; k++){
    float wl = Wl[k*kHD + j], wr = Wr[k*kHD + j];
#pragma unroll
    for (int t = 0; t < XLR_NPB; t++){
      float xv = xs[t*64 + k];
      accl[t] += xv * wl; accr[t] += xv * wr;
    }
  }
#pragma unroll
  for (int t = 0; t < XLR_NPB; t++){
    int n = n0 + t;
    if (n < kN){
      xl_bf[(size_t)n*kHD + j] = f2bf(accl[t]);
      xr_bf[(size_t)n*kHD + j] = f2bf(accr[t]);
    }
  }
}

// ---------------- per-layer: e_loop (bf16) = mean of incoming e rows (contiguous) ------
__global__ __launch_bounds__(256) void k_eloop(const unsigned short* __restrict__ ebf_perm,
    const int* __restrict__ col_start, unsigned short* __restrict__ eloop_bf){
  int wave = threadIdx.x >> 6, lane = threadIdx.x & 63;
  int n = blockIdx.x*4 + wave;
  if (n >= kN) return;
  int s0 = col_start[n], s1 = col_start[n+1];
  float acc = 0.f;
  for (int p = s0; p < s1; p++)
    acc += bf2f(ebf_perm[(size_t)p*64 + lane]);
  int dg = s1 - s0;
  eloop_bf[(size_t)n*64 + lane] = f2bf(acc / (float)(dg > 0 ? dg : 1));
}

// ---------------- per-layer: MFMA score kernel, index-prefetch (chain split) ----------
// Block = 4 waves; wave h = head h; all waves share the block's tile sequence
// t0, t0+G, t0+2G, ... Level-1 (rc2 index) loads for ALL tiles are prefetched
// into registers first; the per-tile loop then issues only level-2 gathers.
#define SC_G 2048
#define SC_MAXT 13            // ceil(NT / SC_G) with NT = 26563
__global__ __launch_bounds__(256) void k_score_mfma(
    const unsigned short* __restrict__ ebf_perm, // [E][64] permuted
    const unsigned short* __restrict__ eloop_bf, // [N][64]
    const unsigned short* __restrict__ xl_bf,    // [N][256]
    const unsigned short* __restrict__ xr_bf,    // [N][256]
    const int2* __restrict__ rc2,
    const unsigned short* __restrict__ WeT,      // [256][64] bf16
    const float* __restrict__ att,               // [4][64]
    float* __restrict__ score)                   // [EN][4] permuted
{
  int lane = threadIdx.x & 63;
  int h    = threadIdx.x >> 6;   // wave id == head
  int e16  = lane & 15;
  int kb   = lane >> 4;

  short8 A[4][2];
  uint2 attp[4];
#pragma unroll
  for (int mt = 0; mt < 4; mt++){
    const unsigned short* arow = WeT + (size_t)(h*64 + mt*16 + e16)*64 + kb*8;
    A[mt][0] = *(const short8*)(arow);
    A[mt][1] = *(const short8*)(arow + 32);
    f32x4 av = *(const f32x4*)(att + h*64 + mt*16 + kb*4);
    attp[mt].x = pack_bf2(av[0], av[1]);
    attp[mt].y = pack_bf2(av[2], av[3]);
  }

  constexpr int NT = (kEN + 15)/16;
  int t0 = blockIdx.x;

  // ---- level-1 prefetch: rc2 for every tile this block owns ----
  int2 rcs[SC_MAXT];
#pragma unroll
  for (int t = 0; t < SC_MAXT; t++){
    int tile = t0 + t*SC_G;
    if (tile < NT){
      int p = tile*16 + e16;
      int pc = (p < kEN) ? p : 0;
      if (pc < kE) rcs[t] = rc2[pc];
      else         rcs[t] = make_int2(pc - kE, pc - kE);
    } else {
      rcs[t] = make_int2(0, 0);
    }
  }

  // ---- per-tile: level-2 gathers + MFMA + reduce ----
#pragma unroll
  for (int t = 0; t < SC_MAXT; t++){
    int tile = t0 + t*SC_G;
    if (tile >= NT) break;
    int p = tile*16 + e16;
    int pc = (p < kEN) ? p : 0;
    bool isE = pc < kE;
    const unsigned short* erow = isE ? (ebf_perm + (size_t)pc*64)
                                     : (eloop_bf + (size_t)(pc - kE)*64);
    short8 b0 = *(const short8*)(erow + kb*8);
    short8 b1 = *(const short8*)(erow + 32 + kb*8);
    const unsigned short* xl_ = xl_bf + (size_t)rcs[t].x*kHD + h*64;
    const unsigned short* xr_ = xr_bf + (size_t)rcs[t].y*kHD + h*64;
    uint2 xlu[4], xru[4];
#pragma unroll
    for (int mt = 0; mt < 4; mt++){
      xlu[mt] = *(const uint2*)(xl_ + mt*16 + kb*4);
      xru[mt] = *(const uint2*)(xr_ + mt*16 + kb*4);
    }
    float sc = 0.f;
#pragma unroll
    for (int mt = 0; mt < 4; mt++){
      f32x4 acc = {0.f,0.f,0.f,0.f};
      acc = __builtin_amdgcn_mfma_f32_16x16x32_bf16(A[mt][0], b0, acc, 0, 0, 0);
      acc = __builtin_amdgcn_mfma_f32_16x16x32_bf16(A[mt][1], b1, acc, 0, 0, 0);
      sc += lrelu02(acc[0] + bf_lo(xlu[mt].x) + bf_lo(xru[mt].x)) * bf_lo(attp[mt].x);
      sc += lrelu02(acc[1] + bf_hi(xlu[mt].x) + bf_hi(xru[mt].x)) * bf_hi(attp[mt].x);
      sc += lrelu02(acc[2] + bf_lo(xlu[mt].y) + bf_lo(xru[mt].y)) * bf_lo(attp[mt].y);
      sc += lrelu02(acc[3] + bf_hi(xlu[mt].y) + bf_hi(xru[mt].y)) * bf_hi(attp[mt].y);
    }
    sc += __shfl_xor(sc, 16);
    sc += __shfl_xor(sc, 32);
    int wp = tile*16 + lane;
    if (lane < 16 && wp < kEN) score[(size_t)wp*kH + h] = sc;
  }
}

// ---------------- per-layer: FUSED segment softmax + aggregate + LN (wave-per-node) ----
__global__ __launch_bounds__(256) void k_agg_ln(
    const unsigned short* __restrict__ xl_bf, const float* __restrict__ score,
    const int* __restrict__ rowp, const int* __restrict__ col_start,
    const float* __restrict__ conv_b, const float* __restrict__ ln_g,
    const float* __restrict__ ln_b, float* __restrict__ x){
  int wv = threadIdx.x >> 6, l = threadIdx.x & 63;
  int n = blockIdx.x*4 + wv;
  if (n >= kN) return;
  int h = l >> 4;
  int s0 = col_start[n], s1 = col_start[n+1];

  float sc_self = score[(size_t)(kE + n)*kH + h];
  float m = sc_self;
  for (int p = s0; p < s1; p++)
    m = fmaxf(m, score[(size_t)p*kH + h]);

  float w0 = __expf(sc_self - m);
  float s = w0;
  float a0, a1, a2, a3;
  {
    uint2 u = *(const uint2*)(xl_bf + (size_t)n*kHD + l*4);
    a0 = w0*bf_lo(u.x); a1 = w0*bf_hi(u.x);
    a2 = w0*bf_lo(u.y); a3 = w0*bf_hi(u.y);
  }
  int p = s0;
  for (; p + 4 <= s1; p += 4){
    float e0 = __expf(score[(size_t)(p+0)*kH + h] - m);
    float e1 = __expf(score[(size_t)(p+1)*kH + h] - m);
    float e2 = __expf(score[(size_t)(p+2)*kH + h] - m);
    float e3 = __expf(score[(size_t)(p+3)*kH + h] - m);
    int r0 = rowp[p], r1 = rowp[p+1], r2 = rowp[p+2], r3 = rowp[p+3];
    uint2 u0 = *(const uint2*)(xl_bf + (size_t)r0*kHD + l*4);
    uint2 u1 = *(const uint2*)(xl_bf + (size_t)r1*kHD + l*4);
    uint2 u2 = *(const uint2*)(xl_bf + (size_t)r2*kHD + l*4);
    uint2 u3 = *(const uint2*)(xl_bf + (size_t)r3*kHD + l*4);
    s += e0 + e1 + e2 + e3;
    a0 += e0*bf_lo(u0.x) + e1*bf_lo(u1.x) + e2*bf_lo(u2.x) + e3*bf_lo(u3.x);
    a1 += e0*bf_hi(u0.x) + e1*bf_hi(u1.x) + e2*bf_hi(u2.x) + e3*bf_hi(u3.x);
    a2 += e0*bf_lo(u0.y) + e1*bf_lo(u1.y) + e2*bf_lo(u2.y) + e3*bf_lo(u3.y);
    a3 += e0*bf_hi(u0.y) + e1*bf_hi(u1.y) + e2*bf_hi(u2.y) + e3*bf_hi(u3.y);
  }
  for (; p < s1; p++){
    float ew = __expf(score[(size_t)p*kH + h] - m);
    int r = rowp[p];
    uint2 u = *(const uint2*)(xl_bf + (size_t)r*kHD + l*4);
    s += ew;
    a0 += ew*bf_lo(u.x); a1 += ew*bf_hi(u.x);
    a2 += ew*bf_lo(u.y); a3 += ew*bf_hi(u.y);
  }
  float inv = 1.f / s;
  a0 *= inv; a1 *= inv; a2 *= inv; a3 *= inv;
  a0 += __shfl_xor(a0, 16); a0 += __shfl_xor(a0, 32);
  a1 += __shfl_xor(a1, 16); a1 += __shfl_xor(a1, 32);
  a2 += __shfl_xor(a2, 16); a2 += __shfl_xor(a2, 32);
  a3 += __shfl_xor(a3, 16); a3 += __shfl_xor(a3, 32);
  int d0 = (l & 15)*4;
  f32x4 cb = *(const f32x4*)(conv_b + d0);
  f32x4 xv = *(const f32x4*)(x + (size_t)n*64 + d0);
  float y0 = xv[0] + a0*0.25f + cb[0];
  float y1 = xv[1] + a1*0.25f + cb[1];
  float y2 = xv[2] + a2*0.25f + cb[2];
  float y3 = xv[3] + a3*0.25f + cb[3];
  float part = y0 + y1 + y2 + y3;
  part += __shfl_xor(part, 1); part += __shfl_xor(part, 2);
  part += __shfl_xor(part, 4); part += __shfl_xor(part, 8);
  float mu = part * (1.f/64.f);
  float f0 = y0 - mu, f1 = y1 - mu, f2 = y2 - mu, f3 = y3 - mu;
  float vp = f0*f0 + f1*f1 + f2*f2 + f3*f3;
  vp += __shfl_xor(vp, 1); vp += __shfl_xor(vp, 2);
  vp += __shfl_xor(vp, 4); vp += __shfl_xor(vp, 8);
  float rstd = rsqrtf(vp * (1.f/64.f) + 1e-5f);
  f32x4 gv = *(const f32x4*)(ln_g + d0);
  f32x4 bv = *(const f32x4*)(ln_b + d0);
  if (l < 16){
    f32x4 o;
    o[0] = fmaxf(f0*rstd*gv[0] + bv[0], 0.f);
    o[1] = fmaxf(f1*rstd*gv[1] + bv[1], 0.f);
    o[2] = fmaxf(f2*rstd*gv[2] + bv[2], 0.f);
    o[3] = fmaxf(f3*rstd*gv[3] + bv[3], 0.f);
    *(f32x4*)(x + (size_t)n*64 + d0) = o;
  }
}

// ---------------- per-layer: P = bf16(x@W1a + b1), Q = bf16(x@W1b) ----------------
#define PQ_NPB 16
__global__ __launch_bounds__(256) void k_pq(const float* __restrict__ x,
    const float* __restrict__ W1, const float* __restrict__ b1,
    unsigned short* __restrict__ P_bf, unsigned short* __restrict__ Q_bf){
  __shared__ float xs[PQ_NPB*64];
  int tid = threadIdx.x;
  int j = tid & 63;
  int s = tid >> 6;
  int n0 = blockIdx.x * PQ_NPB;
  for (int i = tid; i < PQ_NPB*64; i += 256){
    int n = n0 + (i >> 6);
    xs[i] = (n < kN) ? x[(size_t)n*64 + (i & 63)] : 0.f;
  }
  __syncthreads();
  float accP[4], accQ[4];
  float b1v = b1[j];
#pragma unroll
  for (int t = 0; t < 4; t++){ accP[t] = b1v; accQ[t] = 0.f; }
  for (int k = 0; k < 64; k++){
    float wa = W1[k*64 + j];
    float wb = W1[(64 + k)*64 + j];
#pragma unroll
    for (int t = 0; t < 4; t++){
      float xv = xs[(s*4 + t)*64 + k];
      accP[t] += xv * wa; accQ[t] += xv * wb;
    }
  }
#pragma unroll
  for (int t = 0; t < 4; t++){
    int n = n0 + s*4 + t;
    if (n < kN){
      P_bf[(size_t)n*64 + j] = f2bf(accP[t]);
      Q_bf[(size_t)n*64 + j] = f2bf(accQ[t]);
    }
  }
}

// ---------------- per-layer: edge MLP via MFMA (bf16 residual, bf16 P/Q) ----------------
__global__ __launch_bounds__(256) void k_mlp_mfma(
    unsigned short* __restrict__ ebf_perm,
    float* __restrict__ eout_scatter,
    const int* __restrict__ edge_ids,
    const unsigned short* __restrict__ P_bf, const unsigned short* __restrict__ Q_bf,
    const unsigned short* __restrict__ W1cT,  // [64 d][64 k] bf16
    const unsigned short* __restrict__ W2T,   // [64 d][64 k] bf16
    const float* __restrict__ b2,
    const int2* __restrict__ rc2)
{
  __shared__ unsigned short Hl[4][1024];      // 2KB per wave
  int lane = threadIdx.x & 63, wv = threadIdx.x >> 6;
  int e16 = lane & 15, g = lane >> 4;
  int swz = (e16 & 7) << 4;
  char* Hw = (char*)Hl[wv];
  bool last = (eout_scatter != nullptr);

  short8 a1[4][2], a2[4][2];
#pragma unroll
  for (int mt = 0; mt < 4; mt++){
#pragma unroll
    for (int c = 0; c < 2; c++){
      a1[mt][c] = *(const short8*)(W1cT + (size_t)(mt*16 + e16)*64 + c*32 + g*8);
      a2[mt][c] = *(const short8*)(W2T  + (size_t)(mt*16 + e16)*64 + c*32 + g*8);
    }
  }
  f32x4 b2v[4];
#pragma unroll
  for (int mt = 0; mt < 4; mt++) b2v[mt] = *(const f32x4*)(b2 + mt*16 + g*4);

  int wid = (blockIdx.x*256 + threadIdx.x) >> 6;
  int nw  = (gridDim.x*256) >> 6;
  for (int tile = wid; tile < kE/16; tile += nw){
    int p = tile*16 + e16;
    int2 rc = rc2[p];
    const unsigned short* erow = ebf_perm + (size_t)p*64;
    short8 eb0 = *(const short8*)(erow + g*8);
    short8 eb1 = *(const short8*)(erow + 32 + g*8);
    const unsigned short* Pr = P_bf + (size_t)rc.x*64;
    const unsigned short* Qc = Q_bf + (size_t)rc.y*64;

#pragma unroll
    for (int mt = 0; mt < 4; mt++){
      f32x4 acc = {0.f,0.f,0.f,0.f};
      acc = __builtin_amdgcn_mfma_f32_16x16x32_bf16(a1[mt][0], eb0, acc, 0, 0, 0);
      acc = __builtin_amdgcn_mfma_f32_16x16x32_bf16(a1[mt][1], eb1, acc, 0, 0, 0);
      uint2 pu = *(const uint2*)(Pr + mt*16 + g*4);
      uint2 qu = *(const uint2*)(Qc + mt*16 + g*4);
      float h0 = fmaxf(acc[0] + bf_lo(pu.x) + bf_lo(qu.x), 0.f);
      float h1 = fmaxf(acc[1] + bf_hi(pu.x) + bf_hi(qu.x), 0.f);
      float h2 = fmaxf(acc[2] + bf_lo(pu.y) + bf_lo(qu.y), 0.f);
      float h3 = fmaxf(acc[3] + bf_hi(pu.y) + bf_hi(qu.y), 0.f);
      uint2 pk; pk.x = pack_bf2(h0, h1); pk.y = pack_bf2(h2, h3);
      *(uint2*)(Hw + (((e16 << 7) + (mt << 5) + (g << 3)) ^ swz)) = pk;
    }
    short8 hb0 = *(const short8*)(Hw + (((e16 << 7)      + (g << 4)) ^ swz));
    short8 hb1 = *(const short8*)(Hw + (((e16 << 7) + 64 + (g << 4)) ^ swz));

    int oe = last ? edge_ids[p] : 0;
#pragma unroll
    for (int mt = 0; mt < 4; mt++){
      f32x4 o = {0.f,0.f,0.f,0.f};
      o = __builtin_amdgcn_mfma_f32_16x16x32_bf16(a2[mt][0], hb0, o, 0, 0, 0);
      o = __builtin_amdgcn_mfma_f32_16x16x32_bf16(a2[mt][1], hb1, o, 0, 0, 0);
      size_t off = (size_t)p*64 + mt*16 + g*4;
      uint2 u = *(const uint2*)(ebf_perm + off);
      f32x4 eo;
      eo[0] = bf_lo(u.x); eo[1] = bf_hi(u.x); eo[2] = bf_lo(u.y); eo[3] = bf_hi(u.y);
      f32x4 ne;
      ne[0] = fmaxf(eo[0] + o[0] + b2v[mt][0], 0.f);
      ne[1] = fmaxf(eo[1] + o[1] + b2v[mt][1], 0.f);
      ne[2] = fmaxf(eo[2] + o[2] + b2v[mt][2], 0.f);
      ne[3] = fmaxf(eo[3] + o[3] + b2v[mt][3], 0.f);
      if (!last){
        uint2 po; po.x = pack_bf2(ne[0], ne[1]); po.y = pack_bf2(ne[2], ne[3]);
        *(uint2*)(ebf_perm + off) = po;
      } else {
        *(f32x4*)(eout_scatter + (size_t)oe*64 + mt*16 + g*4) = ne;
      }
    }
  }
}

// ---------------- host ----------------
extern "C" void kernel_launch(void* const* d_in, const int* in_sizes, int n_in,
                              void* d_out, int out_size, void* d_ws, size_t ws_size,
                              hipStream_t stream) {
  const float* node_feat = (const float*)d_in[0];
  const int*   edge_idx  = (const int*)d_in[1];
  const float* edge_attr = (const float*)d_in[2];
  const float* W_node = (const float*)d_in[3];
  const float* b_node = (const float*)d_in[4];
  const float* W_edge = (const float*)d_in[5];
  const float* b_edge = (const float*)d_in[6];
  const float* Wl   = (const float*)d_in[7];
  const float* bl   = (const float*)d_in[8];
  const float* Wr   = (const float*)d_in[9];
  const float* br   = (const float*)d_in[10];
  const float* We   = (const float*)d_in[11];
  const float* att  = (const float*)d_in[12];
  const float* cvb  = (const float*)d_in[13];
  const float* lng  = (const float*)d_in[14];
  const float* lnb  = (const float*)d_in[15];
  const float* euW1 = (const float*)d_in[16];
  const float* eub1 = (const float*)d_in[17];
  const float* euW2 = (const float*)d_in[18];
  const float* eub2 = (const float*)d_in[19];

  const int* row = edge_idx;
  const int* col = edge_idx + kE;

  float* x = (float*)d_out;                       // N x 64
  float* e_out = (float*)d_out + (size_t)kN*kD;   // E x 64 (written by final scatter)

  char* p = (char*)d_ws;
  auto carve = [&](size_t bytes)->void*{
    void* r = (void*)p;
    p += (bytes + 255) & ~(size_t)255;
    return r;
  };
  unsigned short* xl_bf    = (unsigned short*)carve((size_t)kN*kHD*2);
  unsigned short* xr_bf    = (unsigned short*)carve((size_t)kN*kHD*2);
  unsigned short* P_bf     = (unsigned short*)carve((size_t)kN*kD*2);
  unsigned short* Q_bf     = (unsigned short*)carve((size_t)kN*kD*2);
  unsigned short* ebf_perm = (unsigned short*)carve((size_t)kE*kD*2);
  unsigned short* eloop_bf = (unsigned short*)carve((size_t)kN*kD*2);
  unsigned short* WeT      = (unsigned short*)carve((size_t)3*kHD*kD*2);
  unsigned short* W1cT     = (unsigned short*)carve((size_t)3*kD*kD*2);
  unsigned short* W2T      = (unsigned short*)carve((size_t)3*kD*kD*2);
  float* score  = (float*)carve((size_t)kEN*kH*4);
  int* deg      = (int*)carve((size_t)kN*4);
  int* col_start= (int*)carve((size_t)(kN+1)*4);
  int* fill     = (int*)carve((size_t)kN*4);
  int* edge_ids = (int*)carve((size_t)kE*4);
  int* rowp     = (int*)carve((size_t)kE*4);
  int2* rc2     = (int2*)carve((size_t)kE*8);

  // CSR build (graph is layer-invariant)
  hipMemsetAsync(deg, 0, (size_t)kN*4, stream);
  hipMemsetAsync(fill, 0, (size_t)kN*4, stream);
  k_deg<<<(kE+255)/256, 256, 0, stream>>>(col, deg);
  k_scan<<<1, 1024, 0, stream>>>(deg, col_start);
  k_fill<<<(kE+255)/256, 256, 0, stream>>>(col, col_start, fill, edge_ids);
  k_permrc<<<(kE+255)/256, 256, 0, stream>>>(edge_ids, row, col, rowp, rc2);

  // weight prepack + initial embeddings
  k_prep<<<192, 256, 0, stream>>>(We, WeT);
  k_prep2<<<48, 256, 0, stream>>>(euW1, euW2, W1cT, W2T);
  k_x0<<<(kN*kD+255)/256, 256, 0, stream>>>(node_feat, W_node, b_node, x);
  k_e0p<<<(int)(((size_t)kE*kD+255)/256), 256, 0, stream>>>(edge_ids, edge_attr, W_edge,
                                                            b_edge, ebf_perm);

  for (int i = 0; i < 3; i++){
    const float* Wl_i  = Wl  + (size_t)i*kD*kHD;
    const float* bl_i  = bl  + (size_t)i*kHD;
    const float* Wr_i  = Wr  + (size_t)i*kD*kHD;
    const float* br_i  = br  + (size_t)i*kHD;
    const float* att_i = att + (size_t)i*kHD;
    const float* cvb_i = cvb + (size_t)i*kD;
    const float* lng_i = lng + (size_t)i*kD;
    const float* lnb_i = lnb + (size_t)i*kD;
    const float* W1_i  = euW1 + (size_t)i*192*64;
    const float* b1_i  = eub1 + (size_t)i*kD;
    const float* b2_i  = eub2 + (size_t)i*kD;
    const unsigned short* WeT_i  = WeT  + (size_t)i*kHD*kD;
    const unsigned short* W1cT_i = W1cT + (size_t)i*kD*kD;
    const unsigned short* W2T_i  = W2T  + (size_t)i*kD*kD;

    k_xlr<<<(kN + XLR_NPB - 1)/XLR_NPB, 256, 0, stream>>>(x, Wl_i, bl_i, Wr_i, br_i,
                                                          xl_bf, xr_bf);
    k_eloop<<<(kN + 3)/4, 256, 0, stream>>>(ebf_perm, col_start, eloop_bf);
    k_score_mfma<<<SC_G, 256, 0, stream>>>(ebf_perm, eloop_bf, xl_bf, xr_bf,
                                           rc2, WeT_i, att_i, score);
    k_agg_ln<<<(kN + 3)/4, 256, 0, stream>>>(xl_bf, score, rowp, col_start,
                                             cvb_i, lng_i, lnb_i, x);
    k_pq<<<(kN + PQ_NPB - 1)/PQ_NPB, 256, 0, stream>>>(x, W1_i, b1_i, P_bf, Q_bf);
    k_mlp_mfma<<<2048, 256, 0, stream>>>(ebf_perm, (i < 2) ? nullptr : e_out,
                                         edge_ids, P_bf, Q_bf, W1cT_i, W2T_i, b2_i,
                                         rc2);
  }
}